// Round 5
// baseline (449.171 us; speedup 1.0000x reference)
//
#include <hip/hip_runtime.h>
#include <hip/hip_bf16.h>
#include <stdint.h>

typedef __bf16 bf16;
typedef __bf16 bf16x4 __attribute__((ext_vector_type(4)));
typedef __bf16 bf16x8 __attribute__((ext_vector_type(8)));
typedef float  f32x4  __attribute__((ext_vector_type(4)));

#define MFMA16(a, b, c) __builtin_amdgcn_mfma_f32_16x16x32_bf16((a), (b), (c), 0, 0, 0)
#define EXP2(x) __builtin_amdgcn_exp2f(x)

__device__ __forceinline__ void gload_lds16(const void* g, void* l) {
  __builtin_amdgcn_global_load_lds((const __attribute__((address_space(1))) void*)g,
                                   (__attribute__((address_space(3))) void*)l,
                                   16, 0, 0);
}

// ---------------------------------------------------------------- prep kernels

__global__ __launch_bounds__(256) void k_cast(const float4* __restrict__ in,
                                              bf16x4* __restrict__ out, int n4) {
  int i = blockIdx.x * 256 + threadIdx.x;
  if (i < n4) {
    float4 v = in[i];
    bf16x4 o = {(bf16)v.x, (bf16)v.y, (bf16)v.z, (bf16)v.w};
    out[i] = o;
  }
}

// in[K][N] (fp32) -> out[N][K] (bf16)
__global__ __launch_bounds__(256) void k_transpose(const float* __restrict__ in,
                                                   bf16* __restrict__ out,
                                                   int K, int N) {
  __shared__ float tile[32][33];
  int n0 = blockIdx.x * 32, k0 = blockIdx.y * 32;
  int tx = threadIdx.x, ty = threadIdx.y;  // (32,8)
#pragma unroll
  for (int i = 0; i < 4; ++i)
    tile[ty + i * 8][tx] = in[(size_t)(k0 + ty + i * 8) * N + n0 + tx];
  __syncthreads();
#pragma unroll
  for (int i = 0; i < 4; ++i)
    out[(size_t)(n0 + ty + i * 8) * K + k0 + tx] = (bf16)tile[tx][ty + i * 8];
}

// ---------------------------------------------------------------- 128x128 GEMM core
// C[M,N] = A[M,1024] @ Bt[N,1024]^T, 4 waves (2x2), each wave 64x64, BK=32.

template <typename Epi>
__device__ __forceinline__ void gemm128(const bf16* __restrict__ A,
                                        const bf16* __restrict__ Bt, Epi epi) {
  __shared__ alignas(16) bf16 As[128][32];
  __shared__ alignas(16) bf16 Bs[128][32];
  const int tid = threadIdx.x;
  const int lane = tid & 63, wv = tid >> 6;
  const int l16 = lane & 15, q4 = lane >> 4;
  const int bm = blockIdx.x * 128, bn = blockIdx.y * 128;
  const int wm = (wv >> 1) * 64, wn = (wv & 1) * 64;

  const f32x4 Z4 = {0.f, 0.f, 0.f, 0.f};
  f32x4 acc[4][4];
#pragma unroll
  for (int mi = 0; mi < 4; ++mi)
#pragma unroll
    for (int ni = 0; ni < 4; ++ni) acc[mi][ni] = Z4;

  const int srow = wv * 32 + (lane >> 2);    // staging row (c=0)
  const int scol = (lane & 3) * 8;           // staging col (elements)
  const bf16* ga = A + (size_t)(bm + srow) * 1024 + scol;
  const bf16* gb = Bt + (size_t)(bn + srow) * 1024 + scol;

  for (int k0 = 0; k0 < 1024; k0 += 32) {
    __syncthreads();  // previous iter's LDS reads done
#pragma unroll
    for (int c = 0; c < 2; ++c) {
      gload_lds16(ga + (size_t)c * 16 * 1024 + k0, &As[wv * 32 + c * 16][0]);
      gload_lds16(gb + (size_t)c * 16 * 1024 + k0, &Bs[wv * 32 + c * 16][0]);
    }
    __syncthreads();  // staging complete (compiler drains vmcnt)

    bf16x8 af[4], bfr[4];
#pragma unroll
    for (int i = 0; i < 4; ++i) {
      af[i]  = *(const bf16x8*)&As[wm + i * 16 + l16][q4 * 8];
      bfr[i] = *(const bf16x8*)&Bs[wn + i * 16 + l16][q4 * 8];
    }
#pragma unroll
    for (int mi = 0; mi < 4; ++mi)
#pragma unroll
      for (int ni = 0; ni < 4; ++ni)
        acc[mi][ni] = MFMA16(af[mi], bfr[ni], acc[mi][ni]);
  }

#pragma unroll
  for (int mi = 0; mi < 4; ++mi)
#pragma unroll
    for (int ni = 0; ni < 4; ++ni)
#pragma unroll
      for (int r = 0; r < 4; ++r) {
        int m = bm + wm + mi * 16 + q4 * 4 + r;
        int n = bn + wn + ni * 16 + l16;
        epi(m, n, acc[mi][ni][r]);
      }
}

// QKV GEMM: n<1024 -> Q (scaled into log2 domain), n<2048 -> K, else -> V transposed.
// Q scale = HEAD_DIM^-0.5 * log2(e) so attention can use exp2 directly.
#define QSCALE (0.125f * 1.44269504088896f)

__global__ __launch_bounds__(256) void k_gemm_qkv(const bf16* __restrict__ xb,
                                                  const bf16* __restrict__ wt,
                                                  bf16* __restrict__ Q,
                                                  bf16* __restrict__ Kd,
                                                  bf16* __restrict__ Vt) {
  gemm128(xb, wt, [=](int m, int n, float v) {
    int b = m >> 11, s = m & 2047;
    int sect = n >> 10, nn = n & 1023;
    int h = nn >> 6, d = nn & 63;
    size_t bh = (size_t)b * 16 + h;
    if (sect == 0)
      Q[(bh * 2048 + s) * 64 + d] = (bf16)(v * QSCALE);
    else if (sect == 1)
      Kd[(bh * 2048 + s) * 64 + d] = (bf16)v;
    else
      Vt[(bh * 64 + d) * 2048 + s] = (bf16)v;
  });
}

// Out GEMM: fp32 output + bias.
__global__ __launch_bounds__(256) void k_gemm_out(const bf16* __restrict__ o2,
                                                  const bf16* __restrict__ wt,
                                                  const float* __restrict__ bias,
                                                  float* __restrict__ out) {
  gemm128(o2, wt, [=](int m, int n, float v) {
    out[(size_t)m * 1024 + n] = v + bias[n];
  });
}

// ---------------------------------------------------------------- flash attention
// Grid (16, 64): x = q-tile of 128 rows, y = (b,h). 4 waves, each owns 32 q-rows.
//
// ROUND-5 FIX: explicit register double-buffering of K/V fragments. Round 4's
// "load then compute" hint was defeated by the allocator (VGPR=76 -> loads
// serialized, 4670 cy/wave-kt vs ~600 issue). Loading tile kt+1 into a ping-
// pong buffer consumed in the NEXT iteration creates a loop-carried dependence
// the compiler cannot sink: every load gets a full compute phase (~600+ cy)
// to complete. Macros (not lambdas) keep all indexing compile-time-constant.
//
// SWAPPED formulation:
//   S^T = mfma(K, Q)   -> lane owns ONE q-row per mf (q = l16).
//   O^T = mfma(V^T, P) -> rescale and 1/l are per-lane scalars.

#define LOAD_KV(KT, KF, VF)                                                       \
  do {                                                                            \
    const int _kt = (KT);                                                         \
    _Pragma("unroll") for (int kk = 0; kk < 2; ++kk)                              \
      _Pragma("unroll") for (int nf = 0; nf < 4; ++nf)                            \
        KF[kk][nf] = *(const bf16x8*)(Kbase +                                     \
            (size_t)(_kt * 64 + nf * 16 + l16) * 64 + kk * 32 + q4 * 8);          \
    _Pragma("unroll") for (int kk = 0; kk < 2; ++kk)                              \
      _Pragma("unroll") for (int df = 0; df < 4; ++df)                            \
        VF[kk][df] = *(const bf16x8*)(Vbase +                                     \
            (size_t)(df * 16 + l16) * 2048 + _kt * 64 + kk * 32 + q4 * 8);        \
  } while (0)

#define COMPUTE_KT(KF, VF)                                                        \
  do {                                                                            \
    f32x4 s_acc[2][4];                                                            \
    _Pragma("unroll") for (int mf = 0; mf < 2; ++mf)                              \
      _Pragma("unroll") for (int nf = 0; nf < 4; ++nf) s_acc[mf][nf] = Z4;        \
    __builtin_amdgcn_s_setprio(1);                                                \
    _Pragma("unroll") for (int kk = 0; kk < 2; ++kk)                              \
      _Pragma("unroll") for (int nf = 0; nf < 4; ++nf)                            \
        _Pragma("unroll") for (int mf = 0; mf < 2; ++mf)                          \
          s_acc[mf][nf] = MFMA16(KF[kk][nf], qf[mf][kk], s_acc[mf][nf]);          \
    __builtin_amdgcn_s_setprio(0);                                                \
    float fmf[2];                                                                 \
    _Pragma("unroll") for (int mf = 0; mf < 2; ++mf) {                            \
      float t = s_acc[mf][0][0];                                                  \
      _Pragma("unroll") for (int nf = 0; nf < 4; ++nf)                            \
        _Pragma("unroll") for (int r = 0; r < 4; ++r)                             \
          if (nf | r) t = fmaxf(t, s_acc[mf][nf][r]);                             \
      t = fmaxf(t, __shfl_xor(t, 16));                                            \
      t = fmaxf(t, __shfl_xor(t, 32));                                            \
      float mn = fmaxf(m_r[mf], t);                                               \
      float f = EXP2(m_r[mf] - mn);                                               \
      float ps = 0.f;                                                             \
      const int row = mf * 16 + l16;                                              \
      _Pragma("unroll") for (int nf = 0; nf < 4; ++nf) {                          \
        float pv0 = EXP2(s_acc[mf][nf][0] - mn);                                  \
        float pv1 = EXP2(s_acc[mf][nf][1] - mn);                                  \
        float pv2 = EXP2(s_acc[mf][nf][2] - mn);                                  \
        float pv3 = EXP2(s_acc[mf][nf][3] - mn);                                  \
        ps += (pv0 + pv1) + (pv2 + pv3);                                          \
        bf16x4 pk = {(bf16)pv0, (bf16)pv1, (bf16)pv2, (bf16)pv3};                 \
        int slot = (nf * 4 + q4) ^ (l16 & 14);                                    \
        *(bf16x4*)&P_lds[wv][row][slot * 4] = pk;                                 \
      }                                                                           \
      ps += __shfl_xor(ps, 16);                                                   \
      ps += __shfl_xor(ps, 32);                                                   \
      l_r[mf] = l_r[mf] * f + ps;                                                 \
      m_r[mf] = mn;                                                               \
      fmf[mf] = f;                                                                \
    }                                                                             \
    _Pragma("unroll") for (int mf = 0; mf < 2; ++mf)                              \
      _Pragma("unroll") for (int df = 0; df < 4; ++df) acc_o[mf][df] *= fmf[mf];  \
    _Pragma("unroll") for (int kk2 = 0; kk2 < 2; ++kk2) {                         \
      bf16x8 pf[2];                                                               \
      _Pragma("unroll") for (int mf = 0; mf < 2; ++mf) {                          \
        int row = mf * 16 + l16;                                                  \
        int pbase = ((kk2 * 8 + q4 * 2) ^ (l16 & 14)) * 4;                        \
        pf[mf] = *(const bf16x8*)&P_lds[wv][row][pbase];                          \
      }                                                                           \
      __builtin_amdgcn_s_setprio(1);                                              \
      _Pragma("unroll") for (int df = 0; df < 4; ++df)                            \
        _Pragma("unroll") for (int mf = 0; mf < 2; ++mf)                          \
          acc_o[mf][df] = MFMA16(VF[kk2][df], pf[mf], acc_o[mf][df]);             \
      __builtin_amdgcn_s_setprio(0);                                              \
    }                                                                             \
  } while (0)

__global__ __launch_bounds__(256, 2) void k_attn(const bf16* __restrict__ Q,
                                                 const bf16* __restrict__ Kd,
                                                 const bf16* __restrict__ Vt,
                                                 bf16* __restrict__ out2) {
  __shared__ alignas(16) bf16 P_lds[4][32][64];
  const int tid = threadIdx.x, lane = tid & 63, wv = tid >> 6;
  const int l16 = lane & 15, q4 = lane >> 4;
  const int bh = blockIdx.y;
  const int b = bh >> 4, h = bh & 15;
  const int q0 = blockIdx.x * 128 + wv * 32;

  // Q fragments in registers for the whole kernel (B-operand role).
  bf16x8 qf[2][2];
#pragma unroll
  for (int mf = 0; mf < 2; ++mf)
#pragma unroll
    for (int kk = 0; kk < 2; ++kk)
      qf[mf][kk] = *(const bf16x8*)(Q + ((size_t)bh * 2048 + q0 + mf * 16 + l16) * 64 +
                                    kk * 32 + q4 * 8);

  const f32x4 Z4 = {0.f, 0.f, 0.f, 0.f};
  float m_r[2], l_r[2];
  f32x4 acc_o[2][4];  // [mf][df]: O^T tile, rows d = df*16+q4*4+r, col q = mf*16+l16
#pragma unroll
  for (int mf = 0; mf < 2; ++mf) {
    m_r[mf] = -__builtin_inff();
    l_r[mf] = 0.f;
#pragma unroll
    for (int df = 0; df < 4; ++df) acc_o[mf][df] = Z4;
  }

  const bf16* Kbase = Kd + (size_t)bh * 2048 * 64;
  const bf16* Vbase = Vt + (size_t)bh * 64 * 2048;

  // Ping-pong fragment buffers (loop-carried: compiler must keep loads in flight).
  bf16x8 kfA[2][4], vfA[2][4], kfB[2][4], vfB[2][4];
  LOAD_KV(0, kfA, vfA);

  for (int kt = 0; kt < 32; kt += 2) {
    LOAD_KV(kt + 1, kfB, vfB);
    COMPUTE_KT(kfA, vfA);
    LOAD_KV(kt + 2 <= 31 ? kt + 2 : 31, kfA, vfA);
    COMPUTE_KT(kfB, vfB);
  }

  // ---- normalize + store with the reference's reshape quirk:
  // (b,h,s,d) -> out2[b][h*128 + s/16][(s%16)*64 + d]
#pragma unroll
  for (int mf = 0; mf < 2; ++mf) {
    float inv = 1.0f / l_r[mf];
    int s = q0 + mf * 16 + l16;
    int row2 = h * 128 + (s >> 4);
    size_t base = ((size_t)b * 2048 + row2) * 1024 + (s & 15) * 64;
#pragma unroll
    for (int df = 0; df < 4; ++df)
#pragma unroll
      for (int r = 0; r < 4; ++r) {
        int d = df * 16 + q4 * 4 + r;
        out2[base + d] = (bf16)(acc_o[mf][df][r] * inv);
      }
  }
}

// ---------------------------------------------------------------- launch

extern "C" void kernel_launch(void* const* d_in, const int* in_sizes, int n_in,
                              void* d_out, int out_size, void* d_ws, size_t ws_size,
                              hipStream_t stream) {
  const float* x     = (const float*)d_in[0];
  const float* w_qkv = (const float*)d_in[1];
  const float* w_out = (const float*)d_in[2];
  const float* b_out = (const float*)d_in[3];
  float* out = (float*)d_out;

  char* ws = (char*)d_ws;
  size_t off = 0;
  auto alloc = [&](size_t bytes) {
    void* p = ws + off;
    off += (bytes + 255) & ~(size_t)255;
    return p;
  };
  bf16* xb    = (bf16*)alloc((size_t)8192 * 1024 * 2);  // reused as out2 later
  bf16* wqkvT = (bf16*)alloc((size_t)3072 * 1024 * 2);
  bf16* woutT = (bf16*)alloc((size_t)1024 * 1024 * 2);
  bf16* Q     = (bf16*)alloc((size_t)64 * 2048 * 64 * 2);
  bf16* Kd    = (bf16*)alloc((size_t)64 * 2048 * 64 * 2);
  bf16* Vt    = (bf16*)alloc((size_t)64 * 64 * 2048 * 2);
  bf16* out2  = xb;  // xb consumed by k_gemm_qkv before k_attn writes out2

  k_cast<<<8192, 256, 0, stream>>>((const float4*)x, (bf16x4*)xb, 8192 * 1024 / 4);
  k_transpose<<<dim3(96, 32), dim3(32, 8), 0, stream>>>(w_qkv, wqkvT, 1024, 3072);
  k_transpose<<<dim3(32, 32), dim3(32, 8), 0, stream>>>(w_out, woutT, 1024, 1024);
  k_gemm_qkv<<<dim3(64, 24), 256, 0, stream>>>(xb, wqkvT, Q, Kd, Vt);
  k_attn<<<dim3(16, 64), 256, 0, stream>>>(Q, Kd, Vt, out2);
  k_gemm_out<<<dim3(64, 8), 256, 0, stream>>>(out2, woutT, b_out, out);
}

// Round 6
// 324.900 us; speedup vs baseline: 1.3825x; 1.3825x over previous
//
#include <hip/hip_runtime.h>
#include <hip/hip_bf16.h>
#include <stdint.h>

typedef __bf16 bf16;
typedef __bf16 bf16x4 __attribute__((ext_vector_type(4)));
typedef __bf16 bf16x8 __attribute__((ext_vector_type(8)));
typedef float  f32x4  __attribute__((ext_vector_type(4)));

#define MFMA16(a, b, c) __builtin_amdgcn_mfma_f32_16x16x32_bf16((a), (b), (c), 0, 0, 0)
#define EXP2(x) __builtin_amdgcn_exp2f(x)

__device__ __forceinline__ void gload_lds16(const void* g, void* l) {
  __builtin_amdgcn_global_load_lds((const __attribute__((address_space(1))) void*)g,
                                   (__attribute__((address_space(3))) void*)l,
                                   16, 0, 0);
}

// ---------------------------------------------------------------- prep kernels

__global__ __launch_bounds__(256) void k_cast(const float4* __restrict__ in,
                                              bf16x4* __restrict__ out, int n4) {
  int i = blockIdx.x * 256 + threadIdx.x;
  if (i < n4) {
    float4 v = in[i];
    bf16x4 o = {(bf16)v.x, (bf16)v.y, (bf16)v.z, (bf16)v.w};
    out[i] = o;
  }
}

// in[K][N] (fp32) -> out[N][K] (bf16)
__global__ __launch_bounds__(256) void k_transpose(const float* __restrict__ in,
                                                   bf16* __restrict__ out,
                                                   int K, int N) {
  __shared__ float tile[32][33];
  int n0 = blockIdx.x * 32, k0 = blockIdx.y * 32;
  int tx = threadIdx.x, ty = threadIdx.y;  // (32,8)
#pragma unroll
  for (int i = 0; i < 4; ++i)
    tile[ty + i * 8][tx] = in[(size_t)(k0 + ty + i * 8) * N + n0 + tx];
  __syncthreads();
#pragma unroll
  for (int i = 0; i < 4; ++i)
    out[(size_t)(n0 + ty + i * 8) * K + k0 + tx] = (bf16)tile[tx][ty + i * 8];
}

// ---------------------------------------------------------------- 128x128 GEMM core
// C[M,N] = A[M,1024] @ Bt[N,1024]^T, 4 waves (2x2), each wave 64x64, BK=32.

template <typename Epi>
__device__ __forceinline__ void gemm128(const bf16* __restrict__ A,
                                        const bf16* __restrict__ Bt, Epi epi) {
  __shared__ alignas(16) bf16 As[128][32];
  __shared__ alignas(16) bf16 Bs[128][32];
  const int tid = threadIdx.x;
  const int lane = tid & 63, wv = tid >> 6;
  const int l16 = lane & 15, q4 = lane >> 4;
  const int bm = blockIdx.x * 128, bn = blockIdx.y * 128;
  const int wm = (wv >> 1) * 64, wn = (wv & 1) * 64;

  const f32x4 Z4 = {0.f, 0.f, 0.f, 0.f};
  f32x4 acc[4][4];
#pragma unroll
  for (int mi = 0; mi < 4; ++mi)
#pragma unroll
    for (int ni = 0; ni < 4; ++ni) acc[mi][ni] = Z4;

  const int srow = wv * 32 + (lane >> 2);    // staging row (c=0)
  const int scol = (lane & 3) * 8;           // staging col (elements)
  const bf16* ga = A + (size_t)(bm + srow) * 1024 + scol;
  const bf16* gb = Bt + (size_t)(bn + srow) * 1024 + scol;

  for (int k0 = 0; k0 < 1024; k0 += 32) {
    __syncthreads();  // previous iter's LDS reads done
#pragma unroll
    for (int c = 0; c < 2; ++c) {
      gload_lds16(ga + (size_t)c * 16 * 1024 + k0, &As[wv * 32 + c * 16][0]);
      gload_lds16(gb + (size_t)c * 16 * 1024 + k0, &Bs[wv * 32 + c * 16][0]);
    }
    __syncthreads();  // staging complete (compiler drains vmcnt)

    bf16x8 af[4], bfr[4];
#pragma unroll
    for (int i = 0; i < 4; ++i) {
      af[i]  = *(const bf16x8*)&As[wm + i * 16 + l16][q4 * 8];
      bfr[i] = *(const bf16x8*)&Bs[wn + i * 16 + l16][q4 * 8];
    }
#pragma unroll
    for (int mi = 0; mi < 4; ++mi)
#pragma unroll
      for (int ni = 0; ni < 4; ++ni)
        acc[mi][ni] = MFMA16(af[mi], bfr[ni], acc[mi][ni]);
  }

#pragma unroll
  for (int mi = 0; mi < 4; ++mi)
#pragma unroll
    for (int ni = 0; ni < 4; ++ni)
#pragma unroll
      for (int r = 0; r < 4; ++r) {
        int m = bm + wm + mi * 16 + q4 * 4 + r;
        int n = bn + wn + ni * 16 + l16;
        epi(m, n, acc[mi][ni][r]);
      }
}

// QKV GEMM: n<1024 -> Q (scaled into log2 domain), n<2048 -> K, else -> V transposed.
// Q scale = HEAD_DIM^-0.5 * log2(e) so attention can use exp2 directly.
#define QSCALE (0.125f * 1.44269504088896f)

__global__ __launch_bounds__(256) void k_gemm_qkv(const bf16* __restrict__ xb,
                                                  const bf16* __restrict__ wt,
                                                  bf16* __restrict__ Q,
                                                  bf16* __restrict__ Kd,
                                                  bf16* __restrict__ Vt) {
  gemm128(xb, wt, [=](int m, int n, float v) {
    int b = m >> 11, s = m & 2047;
    int sect = n >> 10, nn = n & 1023;
    int h = nn >> 6, d = nn & 63;
    size_t bh = (size_t)b * 16 + h;
    if (sect == 0)
      Q[(bh * 2048 + s) * 64 + d] = (bf16)(v * QSCALE);
    else if (sect == 1)
      Kd[(bh * 2048 + s) * 64 + d] = (bf16)v;
    else
      Vt[(bh * 64 + d) * 2048 + s] = (bf16)v;
  });
}

// Out GEMM: fp32 output + bias.
__global__ __launch_bounds__(256) void k_gemm_out(const bf16* __restrict__ o2,
                                                  const bf16* __restrict__ wt,
                                                  const float* __restrict__ bias,
                                                  float* __restrict__ out) {
  gemm128(o2, wt, [=](int m, int n, float v) {
    out[(size_t)m * 1024 + n] = v + bias[n];
  });
}

// ---------------------------------------------------------------- flash attention
// Grid (16, 64): x = q-tile of 128 rows, y = (b,h). 4 waves, each owns 32 q-rows.
//
// ROUND-6 STRUCTURE: K/V staged to LDS via global_load_lds (NO VGPR dest ->
// load-in-flight count no longer limited by the register allocator, which
// clamped r3/r4/r5 at 32/76/128 VGPR and serialized the loads). Double-
// buffered tiles; the single __syncthreads at loop END gives the stage a full
// compute phase (~600cy) to complete (its vmcnt(0) drain lands AFTER compute).
// All 4 waves share the staged tile -> 4x less L2 read traffic.
//
// Swizzle (rule 21, both-sides-or-neither): LDS dest is linear (gload_lds
// requirement); the GLOBAL source slot is XOR-permuted (slot ^= row&7,
// involution); ds_read applies the same XOR. Fragment reads then hit 8
// distinct 16B slots per 8 rows -> 2-way conflict (free) instead of 16-way.
//
// SWAPPED formulation (unchanged): S^T = mfma(K,Q), O^T = mfma(V^T,P);
// per-lane row stats, 2 shfl_xor per reduce; exp2 in log2 domain.

#define STAGE_KV(KT, BUF)                                                        \
  do {                                                                           \
    const int _kt = (KT);                                                        \
    _Pragma("unroll") for (int r = 0; r < 2; ++r) {                              \
      int i = r * 256 + tid;          /* 16B-unit linear index, 0..511 */        \
      int row = i >> 3, sl = i & 7;                                              \
      int gsl = sl ^ (row & 7);                                                  \
      gload_lds16(Kbase + (size_t)(_kt * 64 + row) * 64 + gsl * 8,               \
                  (bf16*)&Ks[BUF][0][0] + (size_t)(r * 256 + wv * 64) * 8);      \
      gload_lds16(Vbase + (size_t)row * 2048 + _kt * 64 + gsl * 8,               \
                  (bf16*)&Vs[BUF][0][0] + (size_t)(r * 256 + wv * 64) * 8);      \
    }                                                                            \
  } while (0)

__global__ __launch_bounds__(256, 3) void k_attn(const bf16* __restrict__ Q,
                                                 const bf16* __restrict__ Kd,
                                                 const bf16* __restrict__ Vt,
                                                 bf16* __restrict__ out2) {
  __shared__ alignas(16) bf16 Ks[2][64][64];
  __shared__ alignas(16) bf16 Vs[2][64][64];
  __shared__ alignas(16) bf16 P_lds[4][32][64];
  const int tid = threadIdx.x, lane = tid & 63, wv = tid >> 6;
  const int l16 = lane & 15, q4 = lane >> 4;
  const int bh = blockIdx.y;
  const int b = bh >> 4, h = bh & 15;
  const int q0 = blockIdx.x * 128 + wv * 32;

  const bf16* Kbase = Kd + (size_t)bh * 2048 * 64;
  const bf16* Vbase = Vt + (size_t)bh * 64 * 2048;

  // Q fragments in registers for the whole kernel (B-operand role).
  bf16x8 qf[2][2];
#pragma unroll
  for (int mf = 0; mf < 2; ++mf)
#pragma unroll
    for (int kk = 0; kk < 2; ++kk)
      qf[mf][kk] = *(const bf16x8*)(Q + ((size_t)bh * 2048 + q0 + mf * 16 + l16) * 64 +
                                    kk * 32 + q4 * 8);

  const f32x4 Z4 = {0.f, 0.f, 0.f, 0.f};
  float m_r[2], l_r[2];
  f32x4 acc_o[2][4];  // [mf][df]: O^T tile, rows d = df*16+q4*4+r, col q = mf*16+l16
#pragma unroll
  for (int mf = 0; mf < 2; ++mf) {
    m_r[mf] = -__builtin_inff();
    l_r[mf] = 0.f;
#pragma unroll
    for (int df = 0; df < 4; ++df) acc_o[mf][df] = Z4;
  }

  STAGE_KV(0, 0);
  __syncthreads();  // drains vmcnt -> buf 0 ready

  for (int kt = 0; kt < 32; ++kt) {
    const int cur = kt & 1;
    // issue async stage of next tile into the other buffer (latency hidden
    // under this iteration's compute; drained by the loop-end barrier)
    STAGE_KV(kt + 1 <= 31 ? kt + 1 : 31, cur ^ 1);

    // ---- fragments from LDS (swizzled slots; 2-way conflicts = free)
    bf16x8 kf[2][4], vfr[2][4];
#pragma unroll
    for (int kk = 0; kk < 2; ++kk)
#pragma unroll
      for (int nf = 0; nf < 4; ++nf)
        kf[kk][nf] = *(const bf16x8*)&Ks[cur][nf * 16 + l16][((kk * 4 + q4) ^ (l16 & 7)) * 8];
#pragma unroll
    for (int kk = 0; kk < 2; ++kk)
#pragma unroll
      for (int df = 0; df < 4; ++df)
        vfr[kk][df] = *(const bf16x8*)&Vs[cur][df * 16 + l16][((kk * 4 + q4) ^ (l16 & 7)) * 8];

    // ---- S^T = K @ Q^T
    f32x4 s_acc[2][4];  // [mf][nf]: rows kpos = nf*16+q4*4+r, col q = mf*16+l16
#pragma unroll
    for (int mf = 0; mf < 2; ++mf)
#pragma unroll
      for (int nf = 0; nf < 4; ++nf) s_acc[mf][nf] = Z4;
    __builtin_amdgcn_s_setprio(1);
#pragma unroll
    for (int kk = 0; kk < 2; ++kk)
#pragma unroll
      for (int nf = 0; nf < 4; ++nf)
#pragma unroll
        for (int mf = 0; mf < 2; ++mf)
          s_acc[mf][nf] = MFMA16(kf[kk][nf], qf[mf][kk], s_acc[mf][nf]);
    __builtin_amdgcn_s_setprio(0);

    // ---- online softmax, one q-row per lane per mf (log2 domain)
    float fmf[2];
#pragma unroll
    for (int mf = 0; mf < 2; ++mf) {
      float t = s_acc[mf][0][0];
#pragma unroll
      for (int nf = 0; nf < 4; ++nf)
#pragma unroll
        for (int r = 0; r < 4; ++r)
          if (nf | r) t = fmaxf(t, s_acc[mf][nf][r]);
      t = fmaxf(t, __shfl_xor(t, 16));
      t = fmaxf(t, __shfl_xor(t, 32));
      float mn = fmaxf(m_r[mf], t);
      float f = EXP2(m_r[mf] - mn);
      float ps = 0.f;
      const int row = mf * 16 + l16;
#pragma unroll
      for (int nf = 0; nf < 4; ++nf) {
        float pv0 = EXP2(s_acc[mf][nf][0] - mn);
        float pv1 = EXP2(s_acc[mf][nf][1] - mn);
        float pv2 = EXP2(s_acc[mf][nf][2] - mn);
        float pv3 = EXP2(s_acc[mf][nf][3] - mn);
        ps += (pv0 + pv1) + (pv2 + pv3);
        bf16x4 pk = {(bf16)pv0, (bf16)pv1, (bf16)pv2, (bf16)pv3};
        int slot = (nf * 4 + q4) ^ (l16 & 14);  // 8B slots, bit0-preserving swizzle
        *(bf16x4*)&P_lds[wv][row][slot * 4] = pk;
      }
      ps += __shfl_xor(ps, 16);
      ps += __shfl_xor(ps, 32);
      l_r[mf] = l_r[mf] * f + ps;
      m_r[mf] = mn;
      fmf[mf] = f;
    }
#pragma unroll
    for (int mf = 0; mf < 2; ++mf)
#pragma unroll
      for (int df = 0; df < 4; ++df) acc_o[mf][df] *= fmf[mf];

    // ---- O^T += V^T @ P^T  (A = V^T rows = d, B = P cols = q, from LDS)
#pragma unroll
    for (int kk2 = 0; kk2 < 2; ++kk2) {
      bf16x8 pf[2];
#pragma unroll
      for (int mf = 0; mf < 2; ++mf) {
        int row = mf * 16 + l16;
        int pbase = ((kk2 * 8 + q4 * 2) ^ (l16 & 14)) * 4;
        pf[mf] = *(const bf16x8*)&P_lds[wv][row][pbase];
      }
      __builtin_amdgcn_s_setprio(1);
#pragma unroll
      for (int df = 0; df < 4; ++df)
#pragma unroll
        for (int mf = 0; mf < 2; ++mf)
          acc_o[mf][df] = MFMA16(vfr[kk2][df], pf[mf], acc_o[mf][df]);
      __builtin_amdgcn_s_setprio(0);
    }

    __syncthreads();  // drains vmcnt(0): next tile staged & ready; orders LDS reuse
  }

  // ---- normalize + store with the reference's reshape quirk:
  // (b,h,s,d) -> out2[b][h*128 + s/16][(s%16)*64 + d]
#pragma unroll
  for (int mf = 0; mf < 2; ++mf) {
    float inv = 1.0f / l_r[mf];
    int s = q0 + mf * 16 + l16;
    int row2 = h * 128 + (s >> 4);
    size_t base = ((size_t)b * 2048 + row2) * 1024 + (s & 15) * 64;
#pragma unroll
    for (int df = 0; df < 4; ++df)
#pragma unroll
      for (int r = 0; r < 4; ++r) {
        int d = df * 16 + q4 * 4 + r;
        out2[base + d] = (bf16)(acc_o[mf][df][r] * inv);
      }
  }
}

// ---------------------------------------------------------------- launch

extern "C" void kernel_launch(void* const* d_in, const int* in_sizes, int n_in,
                              void* d_out, int out_size, void* d_ws, size_t ws_size,
                              hipStream_t stream) {
  const float* x     = (const float*)d_in[0];
  const float* w_qkv = (const float*)d_in[1];
  const float* w_out = (const float*)d_in[2];
  const float* b_out = (const float*)d_in[3];
  float* out = (float*)d_out;

  char* ws = (char*)d_ws;
  size_t off = 0;
  auto alloc = [&](size_t bytes) {
    void* p = ws + off;
    off += (bytes + 255) & ~(size_t)255;
    return p;
  };
  bf16* xb    = (bf16*)alloc((size_t)8192 * 1024 * 2);  // reused as out2 later
  bf16* wqkvT = (bf16*)alloc((size_t)3072 * 1024 * 2);
  bf16* woutT = (bf16*)alloc((size_t)1024 * 1024 * 2);
  bf16* Q     = (bf16*)alloc((size_t)64 * 2048 * 64 * 2);
  bf16* Kd    = (bf16*)alloc((size_t)64 * 2048 * 64 * 2);
  bf16* Vt    = (bf16*)alloc((size_t)64 * 64 * 2048 * 2);
  bf16* out2  = xb;  // xb consumed by k_gemm_qkv before k_attn writes out2

  k_cast<<<8192, 256, 0, stream>>>((const float4*)x, (bf16x4*)xb, 8192 * 1024 / 4);
  k_transpose<<<dim3(96, 32), dim3(32, 8), 0, stream>>>(w_qkv, wqkvT, 1024, 3072);
  k_transpose<<<dim3(32, 32), dim3(32, 8), 0, stream>>>(w_out, woutT, 1024, 1024);
  k_gemm_qkv<<<dim3(64, 24), 256, 0, stream>>>(xb, wqkvT, Q, Kd, Vt);
  k_attn<<<dim3(16, 64), 256, 0, stream>>>(Q, Kd, Vt, out2);
  k_gemm_out<<<dim3(64, 8), 256, 0, stream>>>(out2, woutT, b_out, out);
}

// Round 7
// 298.790 us; speedup vs baseline: 1.5033x; 1.0874x over previous
//
#include <hip/hip_runtime.h>
#include <hip/hip_bf16.h>
#include <stdint.h>

typedef __bf16 bf16;
typedef __bf16 bf16x4 __attribute__((ext_vector_type(4)));
typedef __bf16 bf16x8 __attribute__((ext_vector_type(8)));
typedef float  f32x4  __attribute__((ext_vector_type(4)));

#define MFMA16(a, b, c) __builtin_amdgcn_mfma_f32_16x16x32_bf16((a), (b), (c), 0, 0, 0)
#define EXP2(x) __builtin_amdgcn_exp2f(x)

__device__ __forceinline__ void gload_lds16(const void* g, void* l) {
  __builtin_amdgcn_global_load_lds((const __attribute__((address_space(1))) void*)g,
                                   (__attribute__((address_space(3))) void*)l,
                                   16, 0, 0);
}

// ---------------------------------------------------------------- prep kernels

__global__ __launch_bounds__(256) void k_cast(const float4* __restrict__ in,
                                              bf16x4* __restrict__ out, int n4) {
  int i = blockIdx.x * 256 + threadIdx.x;
  if (i < n4) {
    float4 v = in[i];
    bf16x4 o = {(bf16)v.x, (bf16)v.y, (bf16)v.z, (bf16)v.w};
    out[i] = o;
  }
}

// in[K][N] (fp32) -> out[N][K] (bf16)
__global__ __launch_bounds__(256) void k_transpose(const float* __restrict__ in,
                                                   bf16* __restrict__ out,
                                                   int K, int N) {
  __shared__ float tile[32][33];
  int n0 = blockIdx.x * 32, k0 = blockIdx.y * 32;
  int tx = threadIdx.x, ty = threadIdx.y;  // (32,8)
#pragma unroll
  for (int i = 0; i < 4; ++i)
    tile[ty + i * 8][tx] = in[(size_t)(k0 + ty + i * 8) * N + n0 + tx];
  __syncthreads();
#pragma unroll
  for (int i = 0; i < 4; ++i)
    out[(size_t)(n0 + ty + i * 8) * K + k0 + tx] = (bf16)tile[tx][ty + i * 8];
}

// ---------------------------------------------------------------- 128x128 GEMM core
// C[M,N] = A[M,1024] @ Bt[N,1024]^T, 4 waves (2x2), each wave 64x64, BK=32.
// Epilogue hands each f32x4 fragment (4 CONSECUTIVE m at fixed n) to epi:
// epi(m_base, n, vals) with element r belonging to row m_base+r. This lets
// m-contiguous destinations (V^T) use packed 8B stores instead of 4 scattered
// 2B stores (the round-6 V-path wrote 2B at 4KB stride -> ~4x write-amp).

template <typename Epi>
__device__ __forceinline__ void gemm128(const bf16* __restrict__ A,
                                        const bf16* __restrict__ Bt, Epi epi) {
  __shared__ alignas(16) bf16 As[128][32];
  __shared__ alignas(16) bf16 Bs[128][32];
  const int tid = threadIdx.x;
  const int lane = tid & 63, wv = tid >> 6;
  const int l16 = lane & 15, q4 = lane >> 4;
  const int bm = blockIdx.x * 128, bn = blockIdx.y * 128;
  const int wm = (wv >> 1) * 64, wn = (wv & 1) * 64;

  const f32x4 Z4 = {0.f, 0.f, 0.f, 0.f};
  f32x4 acc[4][4];
#pragma unroll
  for (int mi = 0; mi < 4; ++mi)
#pragma unroll
    for (int ni = 0; ni < 4; ++ni) acc[mi][ni] = Z4;

  const int srow = wv * 32 + (lane >> 2);    // staging row (c=0)
  const int scol = (lane & 3) * 8;           // staging col (elements)
  const bf16* ga = A + (size_t)(bm + srow) * 1024 + scol;
  const bf16* gb = Bt + (size_t)(bn + srow) * 1024 + scol;

  for (int k0 = 0; k0 < 1024; k0 += 32) {
    __syncthreads();  // previous iter's LDS reads done
#pragma unroll
    for (int c = 0; c < 2; ++c) {
      gload_lds16(ga + (size_t)c * 16 * 1024 + k0, &As[wv * 32 + c * 16][0]);
      gload_lds16(gb + (size_t)c * 16 * 1024 + k0, &Bs[wv * 32 + c * 16][0]);
    }
    __syncthreads();  // staging complete (compiler drains vmcnt)

    bf16x8 af[4], bfr[4];
#pragma unroll
    for (int i = 0; i < 4; ++i) {
      af[i]  = *(const bf16x8*)&As[wm + i * 16 + l16][q4 * 8];
      bfr[i] = *(const bf16x8*)&Bs[wn + i * 16 + l16][q4 * 8];
    }
#pragma unroll
    for (int mi = 0; mi < 4; ++mi)
#pragma unroll
      for (int ni = 0; ni < 4; ++ni)
        acc[mi][ni] = MFMA16(af[mi], bfr[ni], acc[mi][ni]);
  }

#pragma unroll
  for (int mi = 0; mi < 4; ++mi)
#pragma unroll
    for (int ni = 0; ni < 4; ++ni) {
      int m0 = bm + wm + mi * 16 + q4 * 4;   // 4 consecutive m: m0..m0+3
      int n  = bn + wn + ni * 16 + l16;
      epi(m0, n, acc[mi][ni]);
    }
}

// QKV GEMM: n<1024 -> Q (scaled into log2 domain), n<2048 -> K, else -> V transposed.
// Q scale = HEAD_DIM^-0.5 * log2(e) so attention can use exp2 directly.
#define QSCALE (0.125f * 1.44269504088896f)

__global__ __launch_bounds__(256) void k_gemm_qkv(const bf16* __restrict__ xb,
                                                  const bf16* __restrict__ wt,
                                                  bf16* __restrict__ Q,
                                                  bf16* __restrict__ Kd,
                                                  bf16* __restrict__ Vt) {
  gemm128(xb, wt, [=](int m0, int n, f32x4 v) {
    int b = m0 >> 11, s0 = m0 & 2047;     // 4 consecutive s in one 2048-block
    int sect = n >> 10, nn = n & 1023;
    int h = nn >> 6, d = nn & 63;
    size_t bh = (size_t)b * 16 + h;
    if (sect == 0) {
#pragma unroll
      for (int r = 0; r < 4; ++r)
        Q[(bh * 2048 + s0 + r) * 64 + d] = (bf16)(v[r] * QSCALE);
    } else if (sect == 1) {
#pragma unroll
      for (int r = 0; r < 4; ++r)
        Kd[(bh * 2048 + s0 + r) * 64 + d] = (bf16)v[r];
    } else {
      // V^T is contiguous in s -> one packed 8B store (was 4x 2B @ 4KB stride)
      bf16x4 pk = {(bf16)v[0], (bf16)v[1], (bf16)v[2], (bf16)v[3]};
      *(bf16x4*)(Vt + (bh * 64 + d) * 2048 + s0) = pk;
    }
  });
}

// Out GEMM: fp32 output + bias.
__global__ __launch_bounds__(256) void k_gemm_out(const bf16* __restrict__ o2,
                                                  const bf16* __restrict__ wt,
                                                  const float* __restrict__ bias,
                                                  float* __restrict__ out) {
  gemm128(o2, wt, [=](int m0, int n, f32x4 v) {
    float bn = bias[n];
#pragma unroll
    for (int r = 0; r < 4; ++r)
      out[(size_t)(m0 + r) * 1024 + n] = v[r] + bn;
  });
}

// ---------------------------------------------------------------- flash attention
// Grid (16, 64): x = q-tile of 128 rows, y = (b,h). 4 waves, each owns 32 q-rows.
// K/V staged to LDS via global_load_lds (no VGPR dest -> allocator can't
// serialize the loads); double-buffered; single loop-end barrier drains the
// stage AFTER a full compute phase. Swizzle: linear LDS dest + XOR-permuted
// GLOBAL source slot + matching XOR on ds_read (rule 21).
// SWAPPED formulation: S^T = mfma(K,Q), O^T = mfma(V^T,P); per-lane row stats.

#define STAGE_KV(KT, BUF)                                                        \
  do {                                                                           \
    const int _kt = (KT);                                                        \
    _Pragma("unroll") for (int r = 0; r < 2; ++r) {                              \
      int i = r * 256 + tid;          /* 16B-unit linear index, 0..511 */        \
      int row = i >> 3, sl = i & 7;                                              \
      int gsl = sl ^ (row & 7);                                                  \
      gload_lds16(Kbase + (size_t)(_kt * 64 + row) * 64 + gsl * 8,               \
                  (bf16*)&Ks[BUF][0][0] + (size_t)(r * 256 + wv * 64) * 8);      \
      gload_lds16(Vbase + (size_t)row * 2048 + _kt * 64 + gsl * 8,               \
                  (bf16*)&Vs[BUF][0][0] + (size_t)(r * 256 + wv * 64) * 8);      \
    }                                                                            \
  } while (0)

__global__ __launch_bounds__(256, 3) void k_attn(const bf16* __restrict__ Q,
                                                 const bf16* __restrict__ Kd,
                                                 const bf16* __restrict__ Vt,
                                                 bf16* __restrict__ out2) {
  __shared__ alignas(16) bf16 Ks[2][64][64];
  __shared__ alignas(16) bf16 Vs[2][64][64];
  __shared__ alignas(16) bf16 P_lds[4][32][64];
  const int tid = threadIdx.x, lane = tid & 63, wv = tid >> 6;
  const int l16 = lane & 15, q4 = lane >> 4;
  const int bh = blockIdx.y;
  const int b = bh >> 4, h = bh & 15;
  const int q0 = blockIdx.x * 128 + wv * 32;

  const bf16* Kbase = Kd + (size_t)bh * 2048 * 64;
  const bf16* Vbase = Vt + (size_t)bh * 64 * 2048;

  // Q fragments in registers for the whole kernel (B-operand role).
  bf16x8 qf[2][2];
#pragma unroll
  for (int mf = 0; mf < 2; ++mf)
#pragma unroll
    for (int kk = 0; kk < 2; ++kk)
      qf[mf][kk] = *(const bf16x8*)(Q + ((size_t)bh * 2048 + q0 + mf * 16 + l16) * 64 +
                                    kk * 32 + q4 * 8);

  const f32x4 Z4 = {0.f, 0.f, 0.f, 0.f};
  float m_r[2], l_r[2];
  f32x4 acc_o[2][4];  // [mf][df]: O^T tile, rows d = df*16+q4*4+r, col q = mf*16+l16
#pragma unroll
  for (int mf = 0; mf < 2; ++mf) {
    m_r[mf] = -__builtin_inff();
    l_r[mf] = 0.f;
#pragma unroll
    for (int df = 0; df < 4; ++df) acc_o[mf][df] = Z4;
  }

  STAGE_KV(0, 0);
  __syncthreads();  // drains vmcnt -> buf 0 ready

  for (int kt = 0; kt < 32; ++kt) {
    const int cur = kt & 1;
    // issue async stage of next tile into the other buffer (latency hidden
    // under this iteration's compute; drained by the loop-end barrier)
    STAGE_KV(kt + 1 <= 31 ? kt + 1 : 31, cur ^ 1);

    // ---- fragments from LDS (swizzled slots; 2-way conflicts = free)
    bf16x8 kf[2][4], vfr[2][4];
#pragma unroll
    for (int kk = 0; kk < 2; ++kk)
#pragma unroll
      for (int nf = 0; nf < 4; ++nf)
        kf[kk][nf] = *(const bf16x8*)&Ks[cur][nf * 16 + l16][((kk * 4 + q4) ^ (l16 & 7)) * 8];
#pragma unroll
    for (int kk = 0; kk < 2; ++kk)
#pragma unroll
      for (int df = 0; df < 4; ++df)
        vfr[kk][df] = *(const bf16x8*)&Vs[cur][df * 16 + l16][((kk * 4 + q4) ^ (l16 & 7)) * 8];

    // ---- S^T = K @ Q^T
    f32x4 s_acc[2][4];  // [mf][nf]: rows kpos = nf*16+q4*4+r, col q = mf*16+l16
#pragma unroll
    for (int mf = 0; mf < 2; ++mf)
#pragma unroll
      for (int nf = 0; nf < 4; ++nf) s_acc[mf][nf] = Z4;
    __builtin_amdgcn_s_setprio(1);
#pragma unroll
    for (int kk = 0; kk < 2; ++kk)
#pragma unroll
      for (int nf = 0; nf < 4; ++nf)
#pragma unroll
        for (int mf = 0; mf < 2; ++mf)
          s_acc[mf][nf] = MFMA16(kf[kk][nf], qf[mf][kk], s_acc[mf][nf]);
    __builtin_amdgcn_s_setprio(0);

    // ---- online softmax, one q-row per lane per mf (log2 domain)
    float fmf[2];
#pragma unroll
    for (int mf = 0; mf < 2; ++mf) {
      float t = s_acc[mf][0][0];
#pragma unroll
      for (int nf = 0; nf < 4; ++nf)
#pragma unroll
        for (int r = 0; r < 4; ++r)
          if (nf | r) t = fmaxf(t, s_acc[mf][nf][r]);
      t = fmaxf(t, __shfl_xor(t, 16));
      t = fmaxf(t, __shfl_xor(t, 32));
      float mn = fmaxf(m_r[mf], t);
      float f = EXP2(m_r[mf] - mn);
      float ps = 0.f;
      const int row = mf * 16 + l16;
#pragma unroll
      for (int nf = 0; nf < 4; ++nf) {
        float pv0 = EXP2(s_acc[mf][nf][0] - mn);
        float pv1 = EXP2(s_acc[mf][nf][1] - mn);
        float pv2 = EXP2(s_acc[mf][nf][2] - mn);
        float pv3 = EXP2(s_acc[mf][nf][3] - mn);
        ps += (pv0 + pv1) + (pv2 + pv3);
        bf16x4 pk = {(bf16)pv0, (bf16)pv1, (bf16)pv2, (bf16)pv3};
        int slot = (nf * 4 + q4) ^ (l16 & 14);  // 8B slots, bit0-preserving swizzle
        *(bf16x4*)&P_lds[wv][row][slot * 4] = pk;
      }
      ps += __shfl_xor(ps, 16);
      ps += __shfl_xor(ps, 32);
      l_r[mf] = l_r[mf] * f + ps;
      m_r[mf] = mn;
      fmf[mf] = f;
    }
#pragma unroll
    for (int mf = 0; mf < 2; ++mf)
#pragma unroll
      for (int df = 0; df < 4; ++df) acc_o[mf][df] *= fmf[mf];

    // ---- O^T += V^T @ P^T  (A = V^T rows = d, B = P cols = q, from LDS)
#pragma unroll
    for (int kk2 = 0; kk2 < 2; ++kk2) {
      bf16x8 pf[2];
#pragma unroll
      for (int mf = 0; mf < 2; ++mf) {
        int row = mf * 16 + l16;
        int pbase = ((kk2 * 8 + q4 * 2) ^ (l16 & 14)) * 4;
        pf[mf] = *(const bf16x8*)&P_lds[wv][row][pbase];
      }
      __builtin_amdgcn_s_setprio(1);
#pragma unroll
      for (int df = 0; df < 4; ++df)
#pragma unroll
        for (int mf = 0; mf < 2; ++mf)
          acc_o[mf][df] = MFMA16(vfr[kk2][df], pf[mf], acc_o[mf][df]);
      __builtin_amdgcn_s_setprio(0);
    }

    __syncthreads();  // drains vmcnt(0): next tile staged & ready; orders LDS reuse
  }

  // ---- normalize + store with the reference's reshape quirk:
  // (b,h,s,d) -> out2[b][h*128 + s/16][(s%16)*64 + d]
#pragma unroll
  for (int mf = 0; mf < 2; ++mf) {
    float inv = 1.0f / l_r[mf];
    int s = q0 + mf * 16 + l16;
    int row2 = h * 128 + (s >> 4);
    size_t base = ((size_t)b * 2048 + row2) * 1024 + (s & 15) * 64;
#pragma unroll
    for (int df = 0; df < 4; ++df)
#pragma unroll
      for (int r = 0; r < 4; ++r) {
        int d = df * 16 + q4 * 4 + r;
        out2[base + d] = (bf16)(acc_o[mf][df][r] * inv);
      }
  }
}

// ---------------------------------------------------------------- launch

extern "C" void kernel_launch(void* const* d_in, const int* in_sizes, int n_in,
                              void* d_out, int out_size, void* d_ws, size_t ws_size,
                              hipStream_t stream) {
  const float* x     = (const float*)d_in[0];
  const float* w_qkv = (const float*)d_in[1];
  const float* w_out = (const float*)d_in[2];
  const float* b_out = (const float*)d_in[3];
  float* out = (float*)d_out;

  char* ws = (char*)d_ws;
  size_t off = 0;
  auto alloc = [&](size_t bytes) {
    void* p = ws + off;
    off += (bytes + 255) & ~(size_t)255;
    return p;
  };
  bf16* xb    = (bf16*)alloc((size_t)8192 * 1024 * 2);  // reused as out2 later
  bf16* wqkvT = (bf16*)alloc((size_t)3072 * 1024 * 2);
  bf16* woutT = (bf16*)alloc((size_t)1024 * 1024 * 2);
  bf16* Q     = (bf16*)alloc((size_t)64 * 2048 * 64 * 2);
  bf16* Kd    = (bf16*)alloc((size_t)64 * 2048 * 64 * 2);
  bf16* Vt    = (bf16*)alloc((size_t)64 * 64 * 2048 * 2);
  bf16* out2  = xb;  // xb consumed by k_gemm_qkv before k_attn writes out2

  k_cast<<<8192, 256, 0, stream>>>((const float4*)x, (bf16x4*)xb, 8192 * 1024 / 4);
  k_transpose<<<dim3(96, 32), dim3(32, 8), 0, stream>>>(w_qkv, wqkvT, 1024, 3072);
  k_transpose<<<dim3(32, 32), dim3(32, 8), 0, stream>>>(w_out, woutT, 1024, 1024);
  k_gemm_qkv<<<dim3(64, 24), 256, 0, stream>>>(xb, wqkvT, Q, Kd, Vt);
  k_attn<<<dim3(16, 64), 256, 0, stream>>>(Q, Kd, Vt, out2);
  k_gemm_out<<<dim3(64, 8), 256, 0, stream>>>(out2, woutT, b_out, out);
}

// Round 8
// 293.969 us; speedup vs baseline: 1.5280x; 1.0164x over previous
//
#include <hip/hip_runtime.h>
#include <hip/hip_bf16.h>
#include <stdint.h>

typedef __bf16 bf16;
typedef __bf16 bf16x4 __attribute__((ext_vector_type(4)));
typedef __bf16 bf16x8 __attribute__((ext_vector_type(8)));
typedef float  f32x4  __attribute__((ext_vector_type(4)));

#define MFMA16(a, b, c) __builtin_amdgcn_mfma_f32_16x16x32_bf16((a), (b), (c), 0, 0, 0)
#define EXP2(x) __builtin_amdgcn_exp2f(x)

__device__ __forceinline__ void gload_lds16(const void* g, void* l) {
  __builtin_amdgcn_global_load_lds((const __attribute__((address_space(1))) void*)g,
                                   (__attribute__((address_space(3))) void*)l,
                                   16, 0, 0);
}

// ---------------------------------------------------------------- prep kernels

__global__ __launch_bounds__(256) void k_cast(const float4* __restrict__ in,
                                              bf16x4* __restrict__ out, int n4) {
  int i = blockIdx.x * 256 + threadIdx.x;
  if (i < n4) {
    float4 v = in[i];
    bf16x4 o = {(bf16)v.x, (bf16)v.y, (bf16)v.z, (bf16)v.w};
    out[i] = o;
  }
}

// in[K][N] (fp32) -> out[N][K] (bf16)
__global__ __launch_bounds__(256) void k_transpose(const float* __restrict__ in,
                                                   bf16* __restrict__ out,
                                                   int K, int N) {
  __shared__ float tile[32][33];
  int n0 = blockIdx.x * 32, k0 = blockIdx.y * 32;
  int tx = threadIdx.x, ty = threadIdx.y;  // (32,8)
#pragma unroll
  for (int i = 0; i < 4; ++i)
    tile[ty + i * 8][tx] = in[(size_t)(k0 + ty + i * 8) * N + n0 + tx];
  __syncthreads();
#pragma unroll
  for (int i = 0; i < 4; ++i)
    out[(size_t)(n0 + ty + i * 8) * K + k0 + tx] = (bf16)tile[tx][ty + i * 8];
}

// ---------------------------------------------------------------- 128x128 GEMM core
// C[M,N] = A[M,1024] @ Bt[N,1024]^T, 4 waves (2x2), each wave 64x64, BK=32.
//
// ROUND-8: stage-ahead DOUBLE-BUFFERED LDS (the structure proven by k_attn):
//   { STAGE(k0+32 -> buf^1); ds_read(buf); 16 MFMA; __syncthreads() }
// The barrier's vmcnt(0) drain lands AFTER a full compute phase instead of
// immediately after issue (old: stage; barrier; compute = ~300-400cy exposed
// drain per iter, 72% of 2-phase time per m233). One barrier per iteration.
// Race-safe: a wave reaches iter i's stage into buf^1 only after the barrier
// ending i-1, which drained every wave's reads of buf^1.
//
// Bank swizzle (rule 21): global source 16B-unit gu = u ^ (row&3), linear LDS
// dest, matching XOR on ds_read -> 2-way conflicts (free) instead of 8-way.
//
// Epilogue hands f32x4 fragments (4 consecutive m at fixed n) to epi.

#define GEMM_STAGE(K0, BUF)                                                \
  do {                                                                     \
    _Pragma("unroll") for (int c = 0; c < 2; ++c) {                        \
      int i = c * 256 + tid;     /* 16B-unit linear index, 0..511 */       \
      int row = i >> 2, u = i & 3;                                         \
      int gu = u ^ (row & 3);                                              \
      gload_lds16(ga_base + (size_t)row * 1024 + (K0) + gu * 8,            \
                  (bf16*)&As[BUF][0][0] + (size_t)i * 8);                  \
      gload_lds16(gb_base + (size_t)row * 1024 + (K0) + gu * 8,            \
                  (bf16*)&Bs[BUF][0][0] + (size_t)i * 8);                  \
    }                                                                      \
  } while (0)

template <typename Epi>
__device__ __forceinline__ void gemm128(const bf16* __restrict__ A,
                                        const bf16* __restrict__ Bt, Epi epi) {
  __shared__ alignas(16) bf16 As[2][128][32];
  __shared__ alignas(16) bf16 Bs[2][128][32];
  const int tid = threadIdx.x;
  const int lane = tid & 63, wv = tid >> 6;
  const int l16 = lane & 15, q4 = lane >> 4;
  const int bm = blockIdx.x * 128, bn = blockIdx.y * 128;
  const int wm = (wv >> 1) * 64, wn = (wv & 1) * 64;

  const bf16* ga_base = A + (size_t)bm * 1024;
  const bf16* gb_base = Bt + (size_t)bn * 1024;

  const f32x4 Z4 = {0.f, 0.f, 0.f, 0.f};
  f32x4 acc[4][4];
#pragma unroll
  for (int mi = 0; mi < 4; ++mi)
#pragma unroll
    for (int ni = 0; ni < 4; ++ni) acc[mi][ni] = Z4;

  GEMM_STAGE(0, 0);
  __syncthreads();  // buf 0 ready

  const int ru = (q4 ^ (l16 & 3)) * 8;  // swizzled read offset (row&3 == l16&3)
  for (int k0 = 0; k0 < 1024; k0 += 32) {
    const int cur = (k0 >> 5) & 1;
    if (k0 + 32 < 1024) GEMM_STAGE(k0 + 32, cur ^ 1);  // uniform branch

    bf16x8 af[4], bfr[4];
#pragma unroll
    for (int i = 0; i < 4; ++i) {
      af[i]  = *(const bf16x8*)&As[cur][wm + i * 16 + l16][ru];
      bfr[i] = *(const bf16x8*)&Bs[cur][wn + i * 16 + l16][ru];
    }
    __builtin_amdgcn_s_setprio(1);
#pragma unroll
    for (int mi = 0; mi < 4; ++mi)
#pragma unroll
      for (int ni = 0; ni < 4; ++ni)
        acc[mi][ni] = MFMA16(af[mi], bfr[ni], acc[mi][ni]);
    __builtin_amdgcn_s_setprio(0);

    __syncthreads();  // drains this iter's stage (after compute) + orders reuse
  }

#pragma unroll
  for (int mi = 0; mi < 4; ++mi)
#pragma unroll
    for (int ni = 0; ni < 4; ++ni) {
      int m0 = bm + wm + mi * 16 + q4 * 4;   // 4 consecutive m: m0..m0+3
      int n  = bn + wn + ni * 16 + l16;
      epi(m0, n, acc[mi][ni]);
    }
}

// QKV GEMM: n<1024 -> Q (scaled into log2 domain), n<2048 -> K, else -> V transposed.
// Q scale = HEAD_DIM^-0.5 * log2(e) so attention can use exp2 directly.
#define QSCALE (0.125f * 1.44269504088896f)

__global__ __launch_bounds__(256) void k_gemm_qkv(const bf16* __restrict__ xb,
                                                  const bf16* __restrict__ wt,
                                                  bf16* __restrict__ Q,
                                                  bf16* __restrict__ Kd,
                                                  bf16* __restrict__ Vt) {
  gemm128(xb, wt, [=](int m0, int n, f32x4 v) {
    int b = m0 >> 11, s0 = m0 & 2047;     // 4 consecutive s in one 2048-block
    int sect = n >> 10, nn = n & 1023;
    int h = nn >> 6, d = nn & 63;
    size_t bh = (size_t)b * 16 + h;
    if (sect == 0) {
#pragma unroll
      for (int r = 0; r < 4; ++r)
        Q[(bh * 2048 + s0 + r) * 64 + d] = (bf16)(v[r] * QSCALE);
    } else if (sect == 1) {
#pragma unroll
      for (int r = 0; r < 4; ++r)
        Kd[(bh * 2048 + s0 + r) * 64 + d] = (bf16)v[r];
    } else {
      // V^T is contiguous in s -> one packed 8B store
      bf16x4 pk = {(bf16)v[0], (bf16)v[1], (bf16)v[2], (bf16)v[3]};
      *(bf16x4*)(Vt + (bh * 64 + d) * 2048 + s0) = pk;
    }
  });
}

// Out GEMM: fp32 output + bias.
__global__ __launch_bounds__(256) void k_gemm_out(const bf16* __restrict__ o2,
                                                  const bf16* __restrict__ wt,
                                                  const float* __restrict__ bias,
                                                  float* __restrict__ out) {
  gemm128(o2, wt, [=](int m0, int n, f32x4 v) {
    float bn = bias[n];
#pragma unroll
    for (int r = 0; r < 4; ++r)
      out[(size_t)(m0 + r) * 1024 + n] = v[r] + bn;
  });
}

// ---------------------------------------------------------------- flash attention
// Grid (16, 64): x = q-tile of 128 rows, y = (b,h). 4 waves, each owns 32 q-rows.
// K/V staged to LDS via global_load_lds (no VGPR dest -> allocator can't
// serialize the loads); double-buffered; single loop-end barrier drains the
// stage AFTER a full compute phase. Swizzle: linear LDS dest + XOR-permuted
// GLOBAL source slot + matching XOR on ds_read (rule 21).
// SWAPPED formulation: S^T = mfma(K,Q), O^T = mfma(V^T,P); per-lane row stats.

#define STAGE_KV(KT, BUF)                                                        \
  do {                                                                           \
    const int _kt = (KT);                                                        \
    _Pragma("unroll") for (int r = 0; r < 2; ++r) {                              \
      int i = r * 256 + tid;          /* 16B-unit linear index, 0..511 */        \
      int row = i >> 3, sl = i & 7;                                              \
      int gsl = sl ^ (row & 7);                                                  \
      gload_lds16(Kbase + (size_t)(_kt * 64 + row) * 64 + gsl * 8,               \
                  (bf16*)&Ks[BUF][0][0] + (size_t)(r * 256 + wv * 64) * 8);      \
      gload_lds16(Vbase + (size_t)row * 2048 + _kt * 64 + gsl * 8,               \
                  (bf16*)&Vs[BUF][0][0] + (size_t)(r * 256 + wv * 64) * 8);      \
    }                                                                            \
  } while (0)

__global__ __launch_bounds__(256, 3) void k_attn(const bf16* __restrict__ Q,
                                                 const bf16* __restrict__ Kd,
                                                 const bf16* __restrict__ Vt,
                                                 bf16* __restrict__ out2) {
  __shared__ alignas(16) bf16 Ks[2][64][64];
  __shared__ alignas(16) bf16 Vs[2][64][64];
  __shared__ alignas(16) bf16 P_lds[4][32][64];
  const int tid = threadIdx.x, lane = tid & 63, wv = tid >> 6;
  const int l16 = lane & 15, q4 = lane >> 4;
  const int bh = blockIdx.y;
  const int b = bh >> 4, h = bh & 15;
  const int q0 = blockIdx.x * 128 + wv * 32;

  const bf16* Kbase = Kd + (size_t)bh * 2048 * 64;
  const bf16* Vbase = Vt + (size_t)bh * 64 * 2048;

  // Q fragments in registers for the whole kernel (B-operand role).
  bf16x8 qf[2][2];
#pragma unroll
  for (int mf = 0; mf < 2; ++mf)
#pragma unroll
    for (int kk = 0; kk < 2; ++kk)
      qf[mf][kk] = *(const bf16x8*)(Q + ((size_t)bh * 2048 + q0 + mf * 16 + l16) * 64 +
                                    kk * 32 + q4 * 8);

  const f32x4 Z4 = {0.f, 0.f, 0.f, 0.f};
  float m_r[2], l_r[2];
  f32x4 acc_o[2][4];  // [mf][df]: O^T tile, rows d = df*16+q4*4+r, col q = mf*16+l16
#pragma unroll
  for (int mf = 0; mf < 2; ++mf) {
    m_r[mf] = -__builtin_inff();
    l_r[mf] = 0.f;
#pragma unroll
    for (int df = 0; df < 4; ++df) acc_o[mf][df] = Z4;
  }

  STAGE_KV(0, 0);
  __syncthreads();  // drains vmcnt -> buf 0 ready

  for (int kt = 0; kt < 32; ++kt) {
    const int cur = kt & 1;
    // issue async stage of next tile into the other buffer (latency hidden
    // under this iteration's compute; drained by the loop-end barrier)
    STAGE_KV(kt + 1 <= 31 ? kt + 1 : 31, cur ^ 1);

    // ---- fragments from LDS (swizzled slots; 2-way conflicts = free)
    bf16x8 kf[2][4], vfr[2][4];
#pragma unroll
    for (int kk = 0; kk < 2; ++kk)
#pragma unroll
      for (int nf = 0; nf < 4; ++nf)
        kf[kk][nf] = *(const bf16x8*)&Ks[cur][nf * 16 + l16][((kk * 4 + q4) ^ (l16 & 7)) * 8];
#pragma unroll
    for (int kk = 0; kk < 2; ++kk)
#pragma unroll
      for (int df = 0; df < 4; ++df)
        vfr[kk][df] = *(const bf16x8*)&Vs[cur][df * 16 + l16][((kk * 4 + q4) ^ (l16 & 7)) * 8];

    // ---- S^T = K @ Q^T
    f32x4 s_acc[2][4];  // [mf][nf]: rows kpos = nf*16+q4*4+r, col q = mf*16+l16
#pragma unroll
    for (int mf = 0; mf < 2; ++mf)
#pragma unroll
      for (int nf = 0; nf < 4; ++nf) s_acc[mf][nf] = Z4;
    __builtin_amdgcn_s_setprio(1);
#pragma unroll
    for (int kk = 0; kk < 2; ++kk)
#pragma unroll
      for (int nf = 0; nf < 4; ++nf)
#pragma unroll
        for (int mf = 0; mf < 2; ++mf)
          s_acc[mf][nf] = MFMA16(kf[kk][nf], qf[mf][kk], s_acc[mf][nf]);
    __builtin_amdgcn_s_setprio(0);

    // ---- online softmax, one q-row per lane per mf (log2 domain)
    float fmf[2];
#pragma unroll
    for (int mf = 0; mf < 2; ++mf) {
      float t = s_acc[mf][0][0];
#pragma unroll
      for (int nf = 0; nf < 4; ++nf)
#pragma unroll
        for (int r = 0; r < 4; ++r)
          if (nf | r) t = fmaxf(t, s_acc[mf][nf][r]);
      t = fmaxf(t, __shfl_xor(t, 16));
      t = fmaxf(t, __shfl_xor(t, 32));
      float mn = fmaxf(m_r[mf], t);
      float f = EXP2(m_r[mf] - mn);
      float ps = 0.f;
      const int row = mf * 16 + l16;
#pragma unroll
      for (int nf = 0; nf < 4; ++nf) {
        float pv0 = EXP2(s_acc[mf][nf][0] - mn);
        float pv1 = EXP2(s_acc[mf][nf][1] - mn);
        float pv2 = EXP2(s_acc[mf][nf][2] - mn);
        float pv3 = EXP2(s_acc[mf][nf][3] - mn);
        ps += (pv0 + pv1) + (pv2 + pv3);
        bf16x4 pk = {(bf16)pv0, (bf16)pv1, (bf16)pv2, (bf16)pv3};
        int slot = (nf * 4 + q4) ^ (l16 & 14);  // 8B slots, bit0-preserving swizzle
        *(bf16x4*)&P_lds[wv][row][slot * 4] = pk;
      }
      ps += __shfl_xor(ps, 16);
      ps += __shfl_xor(ps, 32);
      l_r[mf] = l_r[mf] * f + ps;
      m_r[mf] = mn;
      fmf[mf] = f;
    }
#pragma unroll
    for (int mf = 0; mf < 2; ++mf)
#pragma unroll
      for (int df = 0; df < 4; ++df) acc_o[mf][df] *= fmf[mf];

    // ---- O^T += V^T @ P^T  (A = V^T rows = d, B = P cols = q, from LDS)
#pragma unroll
    for (int kk2 = 0; kk2 < 2; ++kk2) {
      bf16x8 pf[2];
#pragma unroll
      for (int mf = 0; mf < 2; ++mf) {
        int row = mf * 16 + l16;
        int pbase = ((kk2 * 8 + q4 * 2) ^ (l16 & 14)) * 4;
        pf[mf] = *(const bf16x8*)&P_lds[wv][row][pbase];
      }
      __builtin_amdgcn_s_setprio(1);
#pragma unroll
      for (int df = 0; df < 4; ++df)
#pragma unroll
        for (int mf = 0; mf < 2; ++mf)
          acc_o[mf][df] = MFMA16(vfr[kk2][df], pf[mf], acc_o[mf][df]);
      __builtin_amdgcn_s_setprio(0);
    }

    __syncthreads();  // drains vmcnt(0): next tile staged & ready; orders LDS reuse
  }

  // ---- normalize + store with the reference's reshape quirk:
  // (b,h,s,d) -> out2[b][h*128 + s/16][(s%16)*64 + d]
#pragma unroll
  for (int mf = 0; mf < 2; ++mf) {
    float inv = 1.0f / l_r[mf];
    int s = q0 + mf * 16 + l16;
    int row2 = h * 128 + (s >> 4);
    size_t base = ((size_t)b * 2048 + row2) * 1024 + (s & 15) * 64;
#pragma unroll
    for (int df = 0; df < 4; ++df)
#pragma unroll
      for (int r = 0; r < 4; ++r) {
        int d = df * 16 + q4 * 4 + r;
        out2[base + d] = (bf16)(acc_o[mf][df][r] * inv);
      }
  }
}

// ---------------------------------------------------------------- launch

extern "C" void kernel_launch(void* const* d_in, const int* in_sizes, int n_in,
                              void* d_out, int out_size, void* d_ws, size_t ws_size,
                              hipStream_t stream) {
  const float* x     = (const float*)d_in[0];
  const float* w_qkv = (const float*)d_in[1];
  const float* w_out = (const float*)d_in[2];
  const float* b_out = (const float*)d_in[3];
  float* out = (float*)d_out;

  char* ws = (char*)d_ws;
  size_t off = 0;
  auto alloc = [&](size_t bytes) {
    void* p = ws + off;
    off += (bytes + 255) & ~(size_t)255;
    return p;
  };
  bf16* xb    = (bf16*)alloc((size_t)8192 * 1024 * 2);  // reused as out2 later
  bf16* wqkvT = (bf16*)alloc((size_t)3072 * 1024 * 2);
  bf16* woutT = (bf16*)alloc((size_t)1024 * 1024 * 2);
  bf16* Q     = (bf16*)alloc((size_t)64 * 2048 * 64 * 2);
  bf16* Kd    = (bf16*)alloc((size_t)64 * 2048 * 64 * 2);
  bf16* Vt    = (bf16*)alloc((size_t)64 * 64 * 2048 * 2);
  bf16* out2  = xb;  // xb consumed by k_gemm_qkv before k_attn writes out2

  k_cast<<<8192, 256, 0, stream>>>((const float4*)x, (bf16x4*)xb, 8192 * 1024 / 4);
  k_transpose<<<dim3(96, 32), dim3(32, 8), 0, stream>>>(w_qkv, wqkvT, 1024, 3072);
  k_transpose<<<dim3(32, 32), dim3(32, 8), 0, stream>>>(w_out, woutT, 1024, 1024);
  k_gemm_qkv<<<dim3(64, 24), 256, 0, stream>>>(xb, wqkvT, Q, Kd, Vt);
  k_attn<<<dim3(16, 64), 256, 0, stream>>>(Q, Kd, Vt, out2);
  k_gemm_out<<<dim3(64, 8), 256, 0, stream>>>(out2, woutT, b_out, out);
}